// Round 8
// baseline (532.026 us; speedup 1.0000x reference)
//
#include <hip/hip_runtime.h>
#include <hip/hip_bf16.h>
#include <math.h>

// Transformer block, MI355X gfx950.
// R13: attention restructured for occupancy + VALU offload:
//   - KVBLK 128->64, LDS 80->48KB -> 3 blocks/CU (12 waves, was 8); same
//     double-buffer + counted vmwait(4), 32 finer K/V tiles.
//   - softmax denominator via MFMA: accS += mfma(ones, P^T) -> accS[0] is
//     the full per-q denominator (A==1 => D[m][q]=sum_k P^T[k][q]); kills
//     64 VALU adds/tile + the final shfl (VALU was 50% vs MFMA 29%).
// R12: QKV vT fusion w/ LDS-transposed coalesced epilogue; proj 128x256
//   split-K x2; FF1 gemm_8x chunk-pipelined 256x256; FF2 split-K x2.

typedef __bf16 bf16_t;
typedef __bf16 bf16x8 __attribute__((ext_vector_type(8)));
typedef __bf16 bf16x4 __attribute__((ext_vector_type(4)));
typedef float f32x4 __attribute__((ext_vector_type(4)));
typedef float f32x16 __attribute__((ext_vector_type(16)));

#define HID   1024
#define NHEAD 16
#define HD    64
#define EXPD  4096
#define LSEQ  2048
#define BATCH 4
#define MROWS (BATCH * LSEQ)   // 8192

#if __has_builtin(__builtin_amdgcn_exp2f)
#define EXP2F __builtin_amdgcn_exp2f
#else
#define EXP2F exp2f
#endif

__device__ __forceinline__ void gld_lds16(const bf16_t* g, bf16_t* l) {
  __builtin_amdgcn_global_load_lds(
      (const __attribute__((address_space(1))) void*)g,
      (__attribute__((address_space(3))) void*)l, 16, 0, 0);
}

__device__ __forceinline__ void vmwait(int n) {
  // call sites pass constants; dead branches fold away
  if (n == 8)      asm volatile("s_waitcnt vmcnt(8)" ::: "memory");
  else if (n == 4) asm volatile("s_waitcnt vmcnt(4)" ::: "memory");
  else if (n == 3) asm volatile("s_waitcnt vmcnt(3)" ::: "memory");
  else if (n == 0) asm volatile("s_waitcnt vmcnt(0)" ::: "memory");
}

__device__ __forceinline__ void block_bar() {
  asm volatile("" ::: "memory");
  __builtin_amdgcn_s_barrier();
  asm volatile("" ::: "memory");
}

// a'[0:31]=a, a'[32:63]=b[0:31]; b'[0:31]=a[32:63], b'[32:63]=b
__device__ __forceinline__ void swap32(unsigned& a, unsigned& b) {
#if __has_builtin(__builtin_amdgcn_permlane32_swap)
  auto r = __builtin_amdgcn_permlane32_swap(a, b, false, false);
  a = r[0]; b = r[1];
#else
  bool hiL = ((threadIdx.x & 63) >= 32);
  unsigned pa = (unsigned)__shfl_xor((int)a, 32, 64);
  unsigned pb = (unsigned)__shfl_xor((int)b, 32, 64);
  unsigned na = hiL ? pb : a;
  unsigned nb = hiL ? b : pa;
  a = na; b = nb;
#endif
}

__device__ __forceinline__ unsigned pk_bf16(float lo, float hi) {
  bf16_t l = (bf16_t)lo, h = (bf16_t)hi;
  unsigned short ul, uh;
  __builtin_memcpy(&ul, &l, 2);
  __builtin_memcpy(&uh, &h, 2);
  return (unsigned)ul | ((unsigned)uh << 16);
}

__device__ __forceinline__ float gelu_t(float v) {
  // tanh-approx gelu (max |err| ~3e-4)
  float u = v * (0.7978845608028654f + 0.0356774081f * v * v);
  float e = EXP2F(u * 2.885390082f);  // exp(2u)
  float th = (e - 1.f) / (e + 1.f);
  return 0.5f * v * (1.f + th);
}

// ---------------- convert f32 -> bf16 (x) ----------------
__global__ __launch_bounds__(256) void cvt_bf16(const float* __restrict__ in,
                                                bf16_t* __restrict__ out, int n4) {
  int i = blockIdx.x * 256 + threadIdx.x;
  if (i >= n4) return;
  float4 v = ((const float4*)in)[i];
  bf16x4 o;
  o[0] = (bf16_t)v.x; o[1] = (bf16_t)v.y; o[2] = (bf16_t)v.z; o[3] = (bf16_t)v.w;
  ((bf16x4*)out)[i] = o;
}

// ---------------- transpose + convert: W[K][N] f32 -> Wt[N][K] bf16 ----------------
__global__ __launch_bounds__(256) void transpose_cvt(const float* __restrict__ W,
                                                     bf16_t* __restrict__ Wt,
                                                     int K, int N) {
  __shared__ float tile[32][33];
  int n0 = blockIdx.x * 32, k0 = blockIdx.y * 32;
  int tx = threadIdx.x & 31, ty = threadIdx.x >> 5;
#pragma unroll
  for (int i = 0; i < 32; i += 8)
    tile[ty + i][tx] = W[(size_t)(k0 + ty + i) * N + n0 + tx];
  __syncthreads();
#pragma unroll
  for (int i = 0; i < 32; i += 8)
    Wt[(size_t)(n0 + ty + i) * K + k0 + tx] = (bf16_t)tile[tx][ty + i];
}

// ---------------- GEMM: C[M][N] = A[M][K] @ Bt[N][K]^T + bias ----------------
// mode 0: bf16 out; mode 1: gelu then bf16 out; mode 2: f32 out.
// Split-K via gridDim.z: z>0 writes raw f32 partial to C2 (consumer sums).
// vTo (BN==256 only): blocks with n0 >= 2048 transpose their C-tile via LDS
//   and write vTo[((b*16+h)*64+d)*2048 + l] coalesced (QKV V fusion).
// 3-slot LDS rotation, 2-deep prefetch, 1 barrier + 1 counted vmcnt / K-step.
template <int BM, int BN, int NTHR>
__global__ __launch_bounds__(NTHR, (NTHR == 512 ? 4 : 3))
void gemm_k(const bf16_t* __restrict__ A,
            const bf16_t* __restrict__ Bt,
            const float* __restrict__ bias,
            void* __restrict__ C,
            float* __restrict__ C2,
            bf16_t* __restrict__ vTo,
            int M, int N, int K, int mode) {
  constexpr int WC = (NTHR / 64) / 2;        // wave-grid cols (4 or 2)
  constexpr int AL = BM * 4 / NTHR;          // A gld_lds per thread (1 or 2)
  constexpr int BL = BN * 4 / NTHR;          // B gld_lds per thread (2)
  constexpr int LOADS = AL + BL;             // 3 or 4
  constexpr int RSTEP = NTHR >> 2;           // rows covered per load pass
  __shared__ bf16_t smem[3 * BM * 32 + 3 * BN * 32];
  bf16_t* As = smem;
  bf16_t* Bs = smem + 3 * BM * 32;

  // group-M block swizzle: same-XCD blocks (ids = c mod 8) share an A-strip
  const int nbx = gridDim.x;
  int p = blockIdx.y * nbx + blockIdx.x;
  const int GM = 8;
  int group = p / (GM * nbx);
  int idx = p - group * (GM * nbx);
  const int by = group * GM + (idx & (GM - 1));
  const int bx = idx >> 3;  // GM == 8
  const int n0 = bx * BN, m0 = by * BM;

  const int zz = blockIdx.z;
  const int kLen = K / (int)gridDim.z;
  const int kOff = zz * kLen;

  const int t = threadIdx.x;
  const int lane = t & 63, w = t >> 6;
  const int wr = w / WC, wc = w % WC;
  const int quad = lane >> 4, l16 = lane & 15;

  f32x4 acc[4][4];
#pragma unroll
  for (int i = 0; i < 4; ++i)
#pragma unroll
    for (int j = 0; j < 4; ++j) acc[i][j] = (f32x4){0.f, 0.f, 0.f, 0.f};

  // loop-invariant per-lane DMA source offsets (chunk-XOR swizzled k-chunk)
  const int r0 = t >> 2;
  const unsigned ksw = (((unsigned)t & 3u) ^ ((unsigned)(r0 >> 1) & 3u)) * 8u;
  const unsigned offR0 = (unsigned)r0 * (unsigned)K + ksw;
  // row steps of RSTEP (64/128) preserve (r>>1)&3 -> same swizzle

  const bf16_t* aB = A + (size_t)m0 * K + kOff;
  const bf16_t* bB = Bt + (size_t)n0 * K + kOff;

  // loop-invariant LDS frag read offsets (elems); chunk = quad ^ ((row>>1)&3)
  unsigned aoff[4], boff[4];
#pragma unroll
  for (int i = 0; i < 4; ++i) {
    int row = wr * 64 + 16 * i + l16;
    aoff[i] = (unsigned)(row * 32 + (quad ^ ((row >> 1) & 3)) * 8);
  }
#pragma unroll
  for (int j = 0; j < 4; ++j) {
    int row = wc * 64 + 16 * j + l16;
    boff[j] = (unsigned)(row * 32 + (quad ^ ((row >> 1) & 3)) * 8);
  }

  auto stage = [&](int slot, int kk) {
    bf16_t* Asl = As + slot * (BM * 32);
    bf16_t* Bsl = Bs + slot * (BN * 32);
    const bf16_t* aS = aB + kk;
    const bf16_t* bS = bB + kk;
#pragma unroll
    for (int a = 0; a < AL; ++a)
      gld_lds16(aS + offR0 + (size_t)a * RSTEP * K, Asl + (t + a * NTHR) * 8);
#pragma unroll
    for (int b = 0; b < BL; ++b)
      gld_lds16(bS + offR0 + (size_t)b * RSTEP * K, Bsl + (t + b * NTHR) * 8);
  };

  const int NT = kLen >> 5;   // kLen/32 tiles; NT >= 3 required

  // prologue: stage tiles 0,1; wait tile 0
  stage(0, 0);
  stage(1, 32);
  vmwait(LOADS);
  block_bar();

  int cs = 0;  // LDS slot holding tile kt
  for (int kt = 0; kt < NT; ++kt) {
    if (kt < NT - 2) {
      int ss = cs == 0 ? 2 : cs - 1;   // (cs+2)%3 — freed by last barrier
      stage(ss, (kt + 2) * 32);
    }
    const bf16_t* Asl = As + cs * (BM * 32);
    const bf16_t* Bsl = Bs + cs * (BN * 32);
    bf16x8 af[4], bfr[4];
#pragma unroll
    for (int i = 0; i < 4; ++i) af[i] = *(const bf16x8*)(Asl + aoff[i]);
#pragma unroll
    for (int j = 0; j < 4; ++j) bfr[j] = *(const bf16x8*)(Bsl + boff[j]);
    __builtin_amdgcn_s_setprio(1);
#pragma unroll
    for (int i = 0; i < 4; ++i)
#pragma unroll
      for (int j = 0; j < 4; ++j)
        acc[i][j] = __builtin_amdgcn_mfma_f32_16x16x32_bf16(af[i], bfr[j], acc[i][j], 0, 0, 0);
    __builtin_amdgcn_s_setprio(0);
    if (kt < NT - 2)      vmwait(LOADS);  // tile kt+1 landed (kt+2 in flight)
    else if (kt == NT - 2) vmwait(0);     // tile NT-1 landed
    if (kt < NT - 1) block_bar();
    cs = cs == 2 ? 0 : cs + 1;
  }

  if constexpr (BN == 256) {
    if (vTo != nullptr && n0 >= 2048) {
      // V-block: transpose C-tile [128 m][256 n] -> vT rows via LDS.
      // T = [256 c][132 l-pad] bf16 = 67.6KB, overlays As|Bs (73.7KB).
      const int bb = m0 >> 11;
      const int l0b = m0 & 2047;
      block_bar();  // all LDS frag reads of last tile done
      bf16_t* T = smem;
#pragma unroll
      for (int i = 0; i < 4; ++i) {
        int rl = wr * 64 + 16 * i + quad * 4;
#pragma unroll
        for (int j = 0; j < 4; ++j) {
          int c = wc * 64 + 16 * j + l16;
          float bv = bias[n0 + c];
          bf16x4 pk;
#pragma unroll
          for (int r = 0; r < 4; ++r) pk[r] = (bf16_t)(acc[i][j][r] + bv);
          *(bf16x4*)(T + c * 132 + rl) = pk;
        }
      }
      block_bar();
      const int vbase = n0 - 2048;
#pragma unroll
      for (int s = 0; s < 4096 / NTHR; ++s) {
        int id = t + s * NTHR;
        int c = id >> 4, ch = id & 15;
        int hh = (vbase + c) >> 6, dd = (vbase + c) & 63;
        bf16x8 v8 = *(const bf16x8*)(T + c * 132 + ch * 8);
        *(bf16x8*)(vTo + ((size_t)((bb * 16 + hh) * 64 + dd)) * 2048 + l0b + ch * 8) = v8;
      }
      return;
    }
  }

#pragma unroll
  for (int i = 0; i < 4; ++i) {
    int rowb = m0 + wr * 64 + 16 * i + quad * 4;
#pragma unroll
    for (int j = 0; j < 4; ++j) {
      int col = n0 + wc * 64 + 16 * j + l16;
      float bv = (zz == 0) ? bias[col] : 0.f;
#pragma unroll
      for (int r = 0; r < 4; ++r) {
        float v = acc[i][j][r] + bv;
        size_t idx = (size_t)(rowb + r) * N + col;
        if (zz != 0) {
          C2[idx] = v;  // raw f32 partial; consumer sums
        } else if (mode == 0) {
          ((bf16_t*)C)[idx] = (bf16_t)v;
        } else if (mode == 1) {
          ((bf16_t*)C)[idx] = (bf16_t)gelu_t(v);
        } else {
          ((float*)C)[idx] = v;
        }
      }
    }
  }
}

// ---------------- chunk-pipelined GEMM (FF1) ----------------
// C = gelu(A @ Bt^T + bias), bf16 out. 256x256 tile, 8 waves x (128x64),
// 2-slot dbuf (128KB, 1 block/CU). K-tile=64 staged as 4x16KB chunks
// interleaved with MFMA j-groups; two vmcnt(4)+barrier per K-tile.
__global__ __launch_bounds__(512, 2)
void gemm_8x(const bf16_t* __restrict__ A,
             const bf16_t* __restrict__ Bt,
             const float* __restrict__ bias,
             bf16_t* __restrict__ C,
             int M, int N, int K) {
  __shared__ bf16_t smem[65536];  // 128KB: slot s at s*32768:
                                  //   A-klo +0, A-khi +8192, B-klo +16384, B-khi +24576
  const int nbx = gridDim.x;
  int p = blockIdx.y * nbx + blockIdx.x;
  const int GM = 8;
  int group = p / (GM * nbx);
  int idx = p - group * (GM * nbx);
  const int by = group * GM + (idx & (GM - 1));
  const int bx = idx >> 3;
  const int n0 = bx * 256, m0 = by * 256;

  const int t = threadIdx.x;
  const int lane = t & 63, w = t >> 6;
  const int wr = w >> 2, wc = w & 3;     // 2 x 4 wave grid; wave C = 128x64
  const int quad = lane >> 4, l16 = lane & 15;

  f32x4 acc[8][4];
#pragma unroll
  for (int i = 0; i < 8; ++i)
#pragma unroll
    for (int j = 0; j < 4; ++j) acc[i][j] = (f32x4){0.f, 0.f, 0.f, 0.f};

  // DMA source offsets (chunk-XOR pre-swizzle); chunk regions are [*][32]
  const int r0 = t >> 2;
  const unsigned ksw = (((unsigned)t & 3u) ^ ((unsigned)(r0 >> 1) & 3u)) * 8u;
  const unsigned offR = (unsigned)r0 * (unsigned)K + ksw;

  const bf16_t* aB = A + (size_t)m0 * K;
  const bf16_t* bB = Bt + (size_t)n0 * K;

  // frag read offsets within a chunk region ([256 rows][32] swizzled)
  unsigned aoff[8], boff[4];
#pragma unroll
  for (int i = 0; i < 8; ++i) {
    int row = wr * 128 + 16 * i + l16;
    aoff[i] = (unsigned)(row * 32 + (quad ^ ((row >> 1) & 3)) * 8);
  }
#pragma unroll
  for (int j = 0; j < 4; ++j) {
    int row = wc * 64 + 16 * j + l16;
    boff[j] = (unsigned)(16384 + row * 32 + (quad ^ ((row >> 1) & 3)) * 8);
  }

  // stage one 16KB chunk (256 rows x 32 k) = 2 gld_lds passes of 128 rows
  auto stageChunk = [&](const bf16_t* src, int kk, int regionElem) {
    bf16_t* d = smem + regionElem;
    gld_lds16(src + kk + offR, d + t * 8);
    gld_lds16(src + kk + offR + (size_t)128 * K, d + t * 8 + 4096);
  };

  const int NT = K >> 6;   // K/64 tiles; NT >= 2

  // prologue: stage tile 0's 4 chunks; wait for klo pair (khi stays in flight)
  stageChunk(aB, 0, 0);
  stageChunk(bB, 0, 16384);
  stageChunk(aB, 32, 8192);
  stageChunk(bB, 32, 24576);
  vmwait(4);
  block_bar();

  for (int kt = 0; kt < NT; ++kt) {
    const int sb = (kt & 1) * 32768;         // compute slot base
    const int ss = ((kt + 1) & 1) * 32768;   // stage slot base
    const int ktk = (kt + 1) * 64;
    const bool st = (kt + 1 < NT);
    bf16x8 af[8], b0, b1;
    // ==== half 0 (k 0..31 of tile) ====
#pragma unroll
    for (int i = 0; i < 8; ++i) af[i] = *(const bf16x8*)(smem + sb + aoff[i]);
    b0 = *(const bf16x8*)(smem + sb + boff[0]);
    b1 = *(const bf16x8*)(smem + sb + boff[1]);
    if (st) stageChunk(aB, ktk, ss);                      // A-klo of kt+1
    __builtin_amdgcn_s_setprio(1);
#pragma unroll
    for (int i = 0; i < 8; ++i) {
      acc[i][0] = __builtin_amdgcn_mfma_f32_16x16x32_bf16(af[i], b0, acc[i][0], 0, 0, 0);
      acc[i][1] = __builtin_amdgcn_mfma_f32_16x16x32_bf16(af[i], b1, acc[i][1], 0, 0, 0);
    }
    __builtin_amdgcn_s_setprio(0);
    b0 = *(const bf16x8*)(smem + sb + boff[2]);
    b1 = *(const bf16x8*)(smem + sb + boff[3]);
    if (st) stageChunk(bB, ktk, ss + 16384);              // B-klo of kt+1
    __builtin_amdgcn_s_setprio(1);
#pragma unroll
    for (int i = 0; i < 8; ++i) {
      acc[i][2] = __builtin_amdgcn_mfma_f32_16x16x32_bf16(af[i], b0, acc[i][2], 0, 0, 0);
      acc[i][3] = __builtin_amdgcn_mfma_f32_16x16x32_bf16(af[i], b1, acc[i][3], 0, 0, 0);
    }
    __builtin_amdgcn_s_setprio(0);
    // outstanding: Akhi_kt,Bkhi_kt,Aklo',Bklo' (8) -> retire khi pair
    if (st) vmwait(4); else vmwait(0);
    block_bar();
    // ==== half 1 (k 32..63 of tile) ====
#pragma unroll
    for (int i = 0; i < 8; ++i) af[i] = *(const bf16x8*)(smem + sb + 8192 + aoff[i]);
    b0 = *(const bf16x8*)(smem + sb + 8192 + boff[0]);
    b1 = *(const bf16x8*)(smem + sb + 8192 + boff[1]);
    if (st) stageChunk(aB, ktk + 32, ss + 8192);          // A-khi of kt+1
    __builtin_amdgcn_s_setprio(1);
#pragma unroll
    for (int i = 0; i < 8; ++i) {
      acc[i][0] = __builtin_amdgcn_mfma_f32_16x16x32_bf16(af[i], b0, acc[i][0], 0, 0, 0);
      acc[i][1] = __builtin_amdgcn_mfma_f32_16x16x32_bf16(af[i], b1, acc[i][1], 0, 0, 0);
    }
    __builtin_amdgcn_s_setprio(0);
    b0 = *(const bf16x8*)(smem + sb + 8192 + boff[2]);
    b1 = *(const bf16x8*)(smem + sb + 8192 + boff[3]);
    if (st) stageChunk(bB, ktk + 32, ss + 24576);         // B-khi of kt+1
    __builtin_amdgcn_s_setprio(1);
#pragma unroll
    for (int i = 0; i < 8; ++i) {
      acc[i][2] = __builtin_amdgcn_mfma_f32_16x16x32_bf16(af[i], b0, acc[i][2], 0, 0, 0);
      acc[i][3] = __builtin_amdgcn_mfma_f32_16x16x32_bf16(af[i], b1, acc[i][3], 0, 0, 0);
    }
    __builtin_amdgcn_s_setprio(0);
    if (st) {
      // outstanding: Aklo',Bklo',Akhi',Bkhi' (8) -> retire klo pair
      vmwait(4);
      block_bar();
    }
  }

#pragma unroll
  for (int i = 0; i < 8; ++i) {
    int rowb = m0 + wr * 128 + 16 * i + quad * 4;
#pragma unroll
    for (int j = 0; j < 4; ++j) {
      int col = n0 + wc * 64 + 16 * j + l16;
      float bv = bias[col];
#pragma unroll
      for (int r = 0; r < 4; ++r) {
        float v = acc[i][j][r] + bv;
        C[(size_t)(rowb + r) * N + col] = (bf16_t)gelu_t(v);
      }
    }
  }
}

// ---------------- flash attention: 128q/block, operand-swapped, reg-resident P ----------------
// S^T[k][q] = K·(sc·Q)^T ; O^T[d][q] = V^T · P^T. KVBLK=64 double-buffered,
// counted vmwait(4); 48 KB LDS -> 3 blocks/CU; denominator via MFMA(ones).
__global__ __launch_bounds__(256, 3) void attn_kernel(const bf16_t* __restrict__ qkv,
                                                      const bf16_t* __restrict__ vT,
                                                      bf16_t* __restrict__ ob) {
  __shared__ bf16_t smem[24576];  // 48 KB: [Ks(8KB)|Vts(8KB)] x2 slots | Qs(16KB)
  bf16_t* Qs = smem + 16384;      // [128 q][64 d]  unpadded, chunk-XOR swizzle
  const int qt = blockIdx.x, h = blockIdx.y, b = blockIdx.z;
  const int t = threadIdx.x, lane = t & 63, w = t >> 6;
  const int l32 = lane & 31, hi = lane >> 5;
  const size_t RS = 3 * HID;
  const int bh = b * NHEAD + h;

  const bf16_t* qbase = qkv + ((size_t)(b * LSEQ + qt * 128)) * RS + h * HD;
  const bf16_t* kbase = qkv + ((size_t)b * LSEQ) * RS + HID + h * HD;
  const bf16_t* vtbase = vT + (size_t)bh * HD * LSEQ;

  // stage Q [128][64] via DMA, source-swizzled
#pragma unroll
  for (int s = 0; s < 4; ++s) {
    int l = t + s * 256;
    int r = l >> 3, c8 = l & 7;
    gld_lds16(qbase + (size_t)r * RS + ((c8 ^ (r & 7)) * 8), Qs + l * 8);
  }
  __syncthreads();

  // hoist Q B-frags (wave w owns q-tile 32w), pre-scaled
  const float sc = 0.18033688011112042f;  // (1/sqrt(64)) * log2(e)
  bf16x8 bq[4];
  {
    int qrow = 32 * w + l32;
#pragma unroll
    for (int c = 0; c < 4; ++c) {
      int y = 2 * c + hi;
      bf16x8 q8 = *(const bf16x8*)(Qs + qrow * 64 + ((y ^ (qrow & 7)) * 8));
#pragma unroll
      for (int e = 0; e < 8; ++e) q8[e] = (bf16_t)((float)q8[e] * sc);
      bq[c] = q8;
    }
  }

  // ones A-frag: with A==1, mfma gives D[m][q] = sum_k P^T[k][q]
  bf16x8 ones8;
#pragma unroll
  for (int e = 0; e < 8; ++e) ones8[e] = (bf16_t)1.0f;

  // stage K/V tile kt (64 rows) into slot: Ks [64 k][64 d], Vts [64 d][64 l]
  auto stageKV = [&](int slot, int kt) {
    bf16_t* Ks = smem + slot * 8192;
    bf16_t* Vts = Ks + 4096;
#pragma unroll
    for (int s = 0; s < 2; ++s) {
      int l = t + s * 256;
      int r = l >> 3, c8 = l & 7;
      gld_lds16(kbase + (size_t)(kt * 64 + r) * RS + ((c8 ^ (r & 7)) * 8), Ks + l * 8);
      gld_lds16(vtbase + (size_t)r * LSEQ + kt * 64 + ((c8 ^ (r & 7)) * 8), Vts + l * 8);
    }
  };

  f32x16 accO[2], accS;
#pragma unroll
  for (int dt = 0; dt < 2; ++dt)
#pragma unroll
    for (int e = 0; e < 16; ++e) accO[dt][e] = 0.f;
#pragma unroll
  for (int e = 0; e < 16; ++e) accS[e] = 0.f;

  constexpr int NT = LSEQ / 64;  // 32
  stageKV(0, 0);                 // 4 loads in flight

  for (int kt = 0; kt < NT; ++kt) {
    const int cs = kt & 1;
    if (kt + 1 < NT) {
      stageKV(1 - cs, kt + 1);   // issue next tile first (hides K/V latency)
      vmwait(4);                 // tile kt's 4 loads landed; kt+1's in flight
    } else {
      vmwait(0);
    }
    block_bar();                 // all waves' tile-kt loads visible
    const bf16_t* Ks = smem + cs * 8192;
    const bf16_t* Vts = Ks + 4096;

    // S^T rows 0..63 (this tile's k) x this wave's 32 q
    f32x16 s0, s1;
#pragma unroll
    for (int e = 0; e < 16; ++e) { s0[e] = 0.f; s1[e] = 0.f; }
    __builtin_amdgcn_s_setprio(1);
#pragma unroll
    for (int c = 0; c < 4; ++c) {
      int y = 2 * c + hi;
      int r0 = l32;
      bf16x8 a0 = *(const bf16x8*)(Ks + r0 * 64 + ((y ^ (r0 & 7)) * 8));
      s0 = __builtin_amdgcn_mfma_f32_32x32x16_bf16(a0, bq[c], s0, 0, 0, 0);
      int r1 = 32 + l32;
      bf16x8 a1 = *(const bf16x8*)(Ks + r1 * 64 + ((y ^ (r1 & 7)) * 8));
      s1 = __builtin_amdgcn_mfma_f32_32x32x16_bf16(a1, bq[c], s1, 0, 0, 0);
    }
    __builtin_amdgcn_s_setprio(0);

    // p = exp2(s); pack to bf16 pairs; assemble P^T B-frags via permlane swaps
    unsigned pf[2][2][4];  // [stile][c2][reg]
#pragma unroll
    for (int stile = 0; stile < 2; ++stile) {
      f32x16& sv = stile ? s1 : s0;
      float p[16];
#pragma unroll
      for (int e = 0; e < 16; ++e) p[e] = EXP2F(sv[e]);
      unsigned lo[4], hi_[4];
#pragma unroll
      for (int g = 0; g < 4; ++g) {
        lo[g] = pk_bf16(p[4 * g + 0], p[4 * g + 1]);
        hi_[g] = pk_bf16(p[4 * g + 2], p[4 * g + 3]);
      }
#pragma unroll
      for (int c2 = 0; c2 < 2; ++c2) {
        unsigned aL = lo[2 * c2], bL = lo[2 * c2 + 1];
        swap32(aL, bL);
        pf[stile][c2][0] = aL; pf[stile][c2][2] = bL;
        unsigned aH = hi_[2 * c2], bH = hi_[2 * c2 + 1];
        swap32(aH, bH);
        pf[stile][c2][1] = aH; pf[stile][c2][3] = bH;
      }
    }

    // O^T += V^T · P^T ; accS += ones · P^T (denominator)
    __builtin_amdgcn_s_setprio(1);
#pragma unroll
    for (int dt = 0; dt < 2; ++dt)
#pragma unroll
      for (int stile = 0; stile < 2; ++stile)
#pragma unroll
        for (int c2 = 0; c2 < 2; ++c2) {
          int c8v = stile * 4 + c2 * 2 + hi;
          int rv = dt * 32 + l32;
          bf16x8 av = *(const bf16x8*)(Vts + rv * 64 + ((c8v ^ (rv & 7)) * 8));
          union { unsigned u[4]; bf16x8 v; } bp;
          bp.u[0] = pf[stile][c2][0]; bp.u[1] = pf[stile][c2][1];
          bp.u[2] = pf[stile][c2][2]; bp.u[3] = pf[stile][c2][3];
          accO[dt] = __builtin_amdgcn_mfma_f32_32x32x16_bf16(av, bp.v, accO[dt], 0, 0, 0);
        }
#pragma unroll
    for (int stile = 0; stile < 2; ++stile)
#pragma unroll
      for (int c2 = 0; c2 < 2; ++c2) {
        union { unsigned u[4]; bf16x8 v; } bp;
        bp.u[0] = pf[stile][c2][0]; bp.u[1] = pf[stile][c2][1];
        bp.u[2] = pf[stile][c2][2]; bp.u[3] = pf[stile][c2][3];
        accS = __builtin_amdgcn_mfma_f32_32x32x16_bf16(ones8, bp.v, accS, 0, 0, 0);
      }
    __builtin_amdgcn_s_setprio(0);
    block_bar();  // reads of slot cs done -> next iter may stage into it
  }

  // denominator: every accS element = full sum over k for col q = l32
  float inv = 1.f / accS[0];

  // epilogue: O^T -> LDS (stride 68) -> coalesced global
  bf16_t* Osh = smem;
  {
    int q = 32 * w + l32;
#pragma unroll
    for (int dt = 0; dt < 2; ++dt)
#pragma unroll
      for (int e = 0; e < 16; ++e) {
        int d = dt * 32 + (e & 3) + 8 * (e >> 2) + 4 * hi;
        Osh[q * 68 + d] = (bf16_t)(accO[dt][e] * inv);
      }
  }
  __syncthreads();
#pragma unroll
  for (int s = 0; s < 4; ++s) {
    int l = t + s * 256;
    int r = l >> 3, c8 = l & 7;
    bf16x8 v = *(const bf16x8*)(Osh + r * 68 + c8 * 8);
    *(bf16x8*)(ob + ((size_t)(b * LSEQ + qt * 128 + r)) * HID + h * HD + c8 * 8) = v;
  }
}

// ---------------- residual add (2 or 3 way) + LayerNorm ----------------
__global__ __launch_bounds__(256) void resid_ln(const float* __restrict__ X,
                                                const float* __restrict__ Y,
                                                const float* __restrict__ Y2,
                                                const float* __restrict__ g,
                                                const float* __restrict__ be,
                                                float* __restrict__ outf,
                                                bf16_t* __restrict__ outb) {
  const int row = blockIdx.x;
  const int t = threadIdx.x;
  float4 a = ((const float4*)X)[(size_t)row * 256 + t];
  float4 bvec = ((const float4*)Y)[(size_t)row * 256 + t];
  float4 cvec = {0.f, 0.f, 0.f, 0.f};
  if (Y2) cvec = ((const float4*)Y2)[(size_t)row * 256 + t];
  float v0 = a.x + bvec.x + cvec.x, v1 = a.y + bvec.y + cvec.y;
  float v2 = a.z + bvec.z + cvec.z, v3 = a.w + bvec.w + cvec.w;
  float s = v0 + v1 + v2 + v3;
  float s2 = v0 * v0 + v1 * v1 + v2 * v2 + v3 * v3;
#pragma unroll
  for (int msk = 1; msk < 64; msk <<= 1) {
    s += __shfl_xor(s, msk, 64);
    s2 += __shfl_xor(s2, msk, 64);
  }
  __shared__ float red[8];
  int w = t >> 6;
  if ((t & 63) == 0) { red[w] = s; red[w + 4] = s2; }
  __syncthreads();
  s = red[0] + red[1] + red[2] + red[3];
  s2 = red[4] + red[5] + red[6] + red[7];
  float mu = s * (1.f / 1024.f);
  float var = s2 * (1.f / 1024.f) - mu * mu;
  float rstd = rsqrtf(var + 1e-5f);
  float4 gg = ((const float4*)g)[t];
  float4 bb = ((const float4*)be)[t];
  float o0 = (v0 - mu) * rstd * gg.x + bb.x;
  float o1 = (v1 - mu) * rstd * gg.y + bb.y;
  float o2 = (v2 - mu) * rstd * gg.z + bb.z;
  float o3 = (v3 - mu) * rstd * gg.w + bb.w;
  float4 o = {o0, o1, o2, o3};
  ((float4*)outf)[(size_t)row * 256 + t] = o;
  if (outb) {
    bf16x4 ob4;
    ob4[0] = (bf16_t)o0; ob4[1] = (bf16_t)o1; ob4[2] = (bf16_t)o2; ob4[3] = (bf16_t)o3;
    ((bf16x4*)outb)[(size_t)row * 256 + t] = ob4;
  }
}

// ---------------- host ----------------
extern "C" void kernel_launch(void* const* d_in, const int* in_sizes, int n_in,
                              void* d_out, int out_size, void* d_ws, size_t ws_size,
                              hipStream_t stream) {
  const float* x     = (const float*)d_in[0];
  const float* Wqkv  = (const float*)d_in[1];
  const float* bqkv  = (const float*)d_in[2];
  const float* Wproj = (const float*)d_in[3];
  const float* bproj = (const float*)d_in[4];
  const float* W1    = (const float*)d_in[5];
  const float* b1    = (const float*)d_in[6];
  const float* W2    = (const float*)d_in[7];
  const float* b2    = (const float*)d_in[8];
  const float* g1    = (const float*)d_in[9];
  const float* be1   = (const float*)d_in[10];
  const float* g2    = (const float*)d_in[11];
  const float* be2   = (const float*)d_in[12];
  float* out = (float*)d_out;

  // Workspace layout (184 MB, alias-planned):
  //   [0,8M)    w2T      (setup -> FF2)
  //   [8,40M)   h        (proj z1 partial -> LN1 reads+overwrites; -> LN2)
  //   [40,72M)  a_f2     (proj z0 -> LN1; FF2 z0 -> LN2)
  //   [72,136M) qkv_ff   (qkvb: QKV -> attn; ff1b: FF1 -> FF2)
  //   [136,184M) E:
  //     E+0:  wqkvT 6M; E+6M: wprojT 2M; E+8M: w1T 8M; E+16M: xb_ob 16M
  //       -> all dead by FF2: f2b (FF2 z1 partial, 32M) overlays E..E+32M
  //     E+32M: hb/vTg 16M (vTg: QKV -> attn; hb: LN1 -> FF1)
  char* ws = (char*)d_ws;
  bf16_t* w2T    = (bf16_t*)(ws);
  float*  h      = (float*) (ws + ((size_t)8 << 20));
  float*  a_f2   = (float*) (ws + ((size_t)40 << 20));
  bf16_t* qkv_ff = (bf16_t*)(ws + ((size_t)72 << 20));
  char*   E      = ws + ((size_t)136 << 20);
  bf16_t* wqkvT  = (bf16_t*)(E);
  bf16_t* wprojT = (bf16_t*)(E + ((size_t)6 << 20));
  bf16_t* w1T    = (bf16_t*)(E + ((size_t)8 << 20));
  char*   xb_ob  = E + ((size_t)16 << 20);
  bf16_t* hb     = (bf16_t*)(E + ((size_t)32 << 20));
  float*  f2b    = (float*)E;   // FF2 z1 partial: overlays wqkvT..xb_ob (dead)

  bf16_t* xb    = (bf16_t*)xb_ob;
  bf16_t* ob    = (bf16_t*)xb_ob;
  bf16_t* qkvb  = qkv_ff;
  bf16_t* ff1b  = qkv_ff;
  float*  attnf = a_f2;
  float*  ff2f  = a_f2;
  bf16_t* vTg   = hb;  // alias: vT live only qkv->attn; hb live only after LN1

  dim3 blk(256);
  dim3 blk512(512);
  transpose_cvt<<<dim3(3072 / 32, 1024 / 32), blk, 0, stream>>>(Wqkv, wqkvT, 1024, 3072);
  transpose_cvt<<<dim3(1024 / 32, 1024 / 32), blk, 0, stream>>>(Wproj, wprojT, 1024, 1024);
  transpose_cvt<<<dim3(4096 / 32, 1024 / 32), blk, 0, stream>>>(W1, w1T, 1024, 4096);
  transpose_cvt<<<dim3(1024 / 32, 4096 / 32), blk, 0, stream>>>(W2, w2T, 4096, 1024);
  cvt_bf16<<<MROWS * HID / 4 / 256, blk, 0, stream>>>(x, xb, MROWS * HID / 4);

  // QKV: V third transposed via LDS in-epilogue straight to vTg (coalesced)
  gemm_k<128, 256, 512><<<dim3(3072 / 256, MROWS / 128), blk512, 0, stream>>>(
      xb, wqkvT, bqkv, qkvb, nullptr, vTg, MROWS, 3072, 1024, 0);
  attn_kernel<<<dim3(LSEQ / 128, NHEAD, BATCH), blk, 0, stream>>>(qkvb, vTg, ob);
  // proj split-K x2: z0 -> attnf(+bias), z1 -> h (raw partial; LN1 sums)
  gemm_k<128, 256, 512><<<dim3(1024 / 256, MROWS / 128, 2), blk512, 0, stream>>>(
      ob, wprojT, bproj, attnf, h, nullptr, MROWS, 1024, 1024, 2);
  resid_ln<<<MROWS, blk, 0, stream>>>(x, attnf, h, g1, be1, h, hb);
  // FF1: chunk-pipelined 256x256 kernel (gelu fused)
  gemm_8x<<<dim3(4096 / 256, MROWS / 256), blk512, 0, stream>>>(
      hb, w1T, b1, ff1b, MROWS, 4096, 1024);
  // FF2 split-K x2: z0 -> ff2f (+bias), z1 -> f2b (raw partial)
  gemm_k<128, 256, 512><<<dim3(1024 / 256, MROWS / 128, 2), blk512, 0, stream>>>(
      ff1b, w2T, b2, ff2f, f2b, nullptr, MROWS, 1024, 4096, 2);
  resid_ln<<<MROWS, blk, 0, stream>>>(h, ff2f, f2b, g2, be2, out, (bf16_t*)nullptr);
}

// Round 9
// 515.238 us; speedup vs baseline: 1.0326x; 1.0326x over previous
//
#include <hip/hip_runtime.h>
#include <hip/hip_bf16.h>
#include <math.h>

// Transformer block, MI355X gfx950.
// R14: attention QBLK 128->256 (each wave owns 64 q, two B-frag sets):
//   every K/V A-frag LDS read now feeds TWO MFMAs -> LDS read traffic and
//   HBM K/V fetch per unit work halve (LDS floor was ~42us of 95).
//   Grid 512 blocks, 64KB LDS (Qs 32K + 2 K/V slots), launch_bounds(256,2),
//   c=0 MFMA peel consumes hoisted zero vec (kills 64 v_mov/tile).
// R13: KVBLK=64 double-buffer + counted vmwait(4); MFMA(ones) denominator.
// R12: QKV vT fusion w/ LDS-transposed coalesced epilogue; proj 128x256
//   split-K x2; FF1 gemm_8x chunk-pipelined 256x256; FF2 split-K x2.

typedef __bf16 bf16_t;
typedef __bf16 bf16x8 __attribute__((ext_vector_type(8)));
typedef __bf16 bf16x4 __attribute__((ext_vector_type(4)));
typedef float f32x4 __attribute__((ext_vector_type(4)));
typedef float f32x16 __attribute__((ext_vector_type(16)));

#define HID   1024
#define NHEAD 16
#define HD    64
#define EXPD  4096
#define LSEQ  2048
#define BATCH 4
#define MROWS (BATCH * LSEQ)   // 8192

#if __has_builtin(__builtin_amdgcn_exp2f)
#define EXP2F __builtin_amdgcn_exp2f
#else
#define EXP2F exp2f
#endif

__device__ __forceinline__ void gld_lds16(const bf16_t* g, bf16_t* l) {
  __builtin_amdgcn_global_load_lds(
      (const __attribute__((address_space(1))) void*)g,
      (__attribute__((address_space(3))) void*)l, 16, 0, 0);
}

__device__ __forceinline__ void vmwait(int n) {
  // call sites pass constants; dead branches fold away
  if (n == 8)      asm volatile("s_waitcnt vmcnt(8)" ::: "memory");
  else if (n == 4) asm volatile("s_waitcnt vmcnt(4)" ::: "memory");
  else if (n == 3) asm volatile("s_waitcnt vmcnt(3)" ::: "memory");
  else if (n == 0) asm volatile("s_waitcnt vmcnt(0)" ::: "memory");
}

__device__ __forceinline__ void block_bar() {
  asm volatile("" ::: "memory");
  __builtin_amdgcn_s_barrier();
  asm volatile("" ::: "memory");
}

// a'[0:31]=a, a'[32:63]=b[0:31]; b'[0:31]=a[32:63], b'[32:63]=b
__device__ __forceinline__ void swap32(unsigned& a, unsigned& b) {
#if __has_builtin(__builtin_amdgcn_permlane32_swap)
  auto r = __builtin_amdgcn_permlane32_swap(a, b, false, false);
  a = r[0]; b = r[1];
#else
  bool hiL = ((threadIdx.x & 63) >= 32);
  unsigned pa = (unsigned)__shfl_xor((int)a, 32, 64);
  unsigned pb = (unsigned)__shfl_xor((int)b, 32, 64);
  unsigned na = hiL ? pb : a;
  unsigned nb = hiL ? b : pa;
  a = na; b = nb;
#endif
}

__device__ __forceinline__ unsigned pk_bf16(float lo, float hi) {
  bf16_t l = (bf16_t)lo, h = (bf16_t)hi;
  unsigned short ul, uh;
  __builtin_memcpy(&ul, &l, 2);
  __builtin_memcpy(&uh, &h, 2);
  return (unsigned)ul | ((unsigned)uh << 16);
}

__device__ __forceinline__ float gelu_t(float v) {
  // tanh-approx gelu (max |err| ~3e-4)
  float u = v * (0.7978845608028654f + 0.0356774081f * v * v);
  float e = EXP2F(u * 2.885390082f);  // exp(2u)
  float th = (e - 1.f) / (e + 1.f);
  return 0.5f * v * (1.f + th);
}

// ---------------- convert f32 -> bf16 (x) ----------------
__global__ __launch_bounds__(256) void cvt_bf16(const float* __restrict__ in,
                                                bf16_t* __restrict__ out, int n4) {
  int i = blockIdx.x * 256 + threadIdx.x;
  if (i >= n4) return;
  float4 v = ((const float4*)in)[i];
  bf16x4 o;
  o[0] = (bf16_t)v.x; o[1] = (bf16_t)v.y; o[2] = (bf16_t)v.z; o[3] = (bf16_t)v.w;
  ((bf16x4*)out)[i] = o;
}

// ---------------- transpose + convert: W[K][N] f32 -> Wt[N][K] bf16 ----------------
__global__ __launch_bounds__(256) void transpose_cvt(const float* __restrict__ W,
                                                     bf16_t* __restrict__ Wt,
                                                     int K, int N) {
  __shared__ float tile[32][33];
  int n0 = blockIdx.x * 32, k0 = blockIdx.y * 32;
  int tx = threadIdx.x & 31, ty = threadIdx.x >> 5;
#pragma unroll
  for (int i = 0; i < 32; i += 8)
    tile[ty + i][tx] = W[(size_t)(k0 + ty + i) * N + n0 + tx];
  __syncthreads();
#pragma unroll
  for (int i = 0; i < 32; i += 8)
    Wt[(size_t)(n0 + ty + i) * K + k0 + tx] = (bf16_t)tile[tx][ty + i];
}

// ---------------- GEMM: C[M][N] = A[M][K] @ Bt[N][K]^T + bias ----------------
// mode 0: bf16 out; mode 1: gelu then bf16 out; mode 2: f32 out.
// Split-K via gridDim.z: z>0 writes raw f32 partial to C2 (consumer sums).
// vTo (BN==256 only): blocks with n0 >= 2048 transpose their C-tile via LDS
//   and write vTo[((b*16+h)*64+d)*2048 + l] coalesced (QKV V fusion).
// 3-slot LDS rotation, 2-deep prefetch, 1 barrier + 1 counted vmcnt / K-step.
template <int BM, int BN, int NTHR>
__global__ __launch_bounds__(NTHR, (NTHR == 512 ? 4 : 3))
void gemm_k(const bf16_t* __restrict__ A,
            const bf16_t* __restrict__ Bt,
            const float* __restrict__ bias,
            void* __restrict__ C,
            float* __restrict__ C2,
            bf16_t* __restrict__ vTo,
            int M, int N, int K, int mode) {
  constexpr int WC = (NTHR / 64) / 2;        // wave-grid cols (4 or 2)
  constexpr int AL = BM * 4 / NTHR;          // A gld_lds per thread (1 or 2)
  constexpr int BL = BN * 4 / NTHR;          // B gld_lds per thread (2)
  constexpr int LOADS = AL + BL;             // 3 or 4
  constexpr int RSTEP = NTHR >> 2;           // rows covered per load pass
  __shared__ bf16_t smem[3 * BM * 32 + 3 * BN * 32];
  bf16_t* As = smem;
  bf16_t* Bs = smem + 3 * BM * 32;

  // group-M block swizzle: same-XCD blocks (ids = c mod 8) share an A-strip
  const int nbx = gridDim.x;
  int p = blockIdx.y * nbx + blockIdx.x;
  const int GM = 8;
  int group = p / (GM * nbx);
  int idx = p - group * (GM * nbx);
  const int by = group * GM + (idx & (GM - 1));
  const int bx = idx >> 3;  // GM == 8
  const int n0 = bx * BN, m0 = by * BM;

  const int zz = blockIdx.z;
  const int kLen = K / (int)gridDim.z;
  const int kOff = zz * kLen;

  const int t = threadIdx.x;
  const int lane = t & 63, w = t >> 6;
  const int wr = w / WC, wc = w % WC;
  const int quad = lane >> 4, l16 = lane & 15;

  f32x4 acc[4][4];
#pragma unroll
  for (int i = 0; i < 4; ++i)
#pragma unroll
    for (int j = 0; j < 4; ++j) acc[i][j] = (f32x4){0.f, 0.f, 0.f, 0.f};

  // loop-invariant per-lane DMA source offsets (chunk-XOR swizzled k-chunk)
  const int r0 = t >> 2;
  const unsigned ksw = (((unsigned)t & 3u) ^ ((unsigned)(r0 >> 1) & 3u)) * 8u;
  const unsigned offR0 = (unsigned)r0 * (unsigned)K + ksw;
  // row steps of RSTEP (64/128) preserve (r>>1)&3 -> same swizzle

  const bf16_t* aB = A + (size_t)m0 * K + kOff;
  const bf16_t* bB = Bt + (size_t)n0 * K + kOff;

  // loop-invariant LDS frag read offsets (elems); chunk = quad ^ ((row>>1)&3)
  unsigned aoff[4], boff[4];
#pragma unroll
  for (int i = 0; i < 4; ++i) {
    int row = wr * 64 + 16 * i + l16;
    aoff[i] = (unsigned)(row * 32 + (quad ^ ((row >> 1) & 3)) * 8);
  }
#pragma unroll
  for (int j = 0; j < 4; ++j) {
    int row = wc * 64 + 16 * j + l16;
    boff[j] = (unsigned)(row * 32 + (quad ^ ((row >> 1) & 3)) * 8);
  }

  auto stage = [&](int slot, int kk) {
    bf16_t* Asl = As + slot * (BM * 32);
    bf16_t* Bsl = Bs + slot * (BN * 32);
    const bf16_t* aS = aB + kk;
    const bf16_t* bS = bB + kk;
#pragma unroll
    for (int a = 0; a < AL; ++a)
      gld_lds16(aS + offR0 + (size_t)a * RSTEP * K, Asl + (t + a * NTHR) * 8);
#pragma unroll
    for (int b = 0; b < BL; ++b)
      gld_lds16(bS + offR0 + (size_t)b * RSTEP * K, Bsl + (t + b * NTHR) * 8);
  };

  const int NT = kLen >> 5;   // kLen/32 tiles; NT >= 3 required

  // prologue: stage tiles 0,1; wait tile 0
  stage(0, 0);
  stage(1, 32);
  vmwait(LOADS);
  block_bar();

  int cs = 0;  // LDS slot holding tile kt
  for (int kt = 0; kt < NT; ++kt) {
    if (kt < NT - 2) {
      int ss = cs == 0 ? 2 : cs - 1;   // (cs+2)%3 — freed by last barrier
      stage(ss, (kt + 2) * 32);
    }
    const bf16_t* Asl = As + cs * (BM * 32);
    const bf16_t* Bsl = Bs + cs * (BN * 32);
    bf16x8 af[4], bfr[4];
#pragma unroll
    for (int i = 0; i < 4; ++i) af[i] = *(const bf16x8*)(Asl + aoff[i]);
#pragma unroll
    for (int j = 0; j < 4; ++j) bfr[j] = *(const bf16x8*)(Bsl + boff[j]);
    __builtin_amdgcn_s_setprio(1);
#pragma unroll
    for (int i = 0; i < 4; ++i)
#pragma unroll
      for (int j = 0; j < 4; ++j)
        acc[i][j] = __builtin_amdgcn_mfma_f32_16x16x32_bf16(af[i], bfr[j], acc[i][j], 0, 0, 0);
    __builtin_amdgcn_s_setprio(0);
    if (kt < NT - 2)      vmwait(LOADS);  // tile kt+1 landed (kt+2 in flight)
    else if (kt == NT - 2) vmwait(0);     // tile NT-1 landed
    if (kt < NT - 1) block_bar();
    cs = cs == 2 ? 0 : cs + 1;
  }

  if constexpr (BN == 256) {
    if (vTo != nullptr && n0 >= 2048) {
      // V-block: transpose C-tile [128 m][256 n] -> vT rows via LDS.
      // T = [256 c][132 l-pad] bf16 = 67.6KB, overlays As|Bs (73.7KB).
      const int bb = m0 >> 11;
      const int l0b = m0 & 2047;
      block_bar();  // all LDS frag reads of last tile done
      bf16_t* T = smem;
#pragma unroll
      for (int i = 0; i < 4; ++i) {
        int rl = wr * 64 + 16 * i + quad * 4;
#pragma unroll
        for (int j = 0; j < 4; ++j) {
          int c = wc * 64 + 16 * j + l16;
          float bv = bias[n0 + c];
          bf16x4 pk;
#pragma unroll
          for (int r = 0; r < 4; ++r) pk[r] = (bf16_t)(acc[i][j][r] + bv);
          *(bf16x4*)(T + c * 132 + rl) = pk;
        }
      }
      block_bar();
      const int vbase = n0 - 2048;
#pragma unroll
      for (int s = 0; s < 4096 / NTHR; ++s) {
        int id = t + s * NTHR;
        int c = id >> 4, ch = id & 15;
        int hh = (vbase + c) >> 6, dd = (vbase + c) & 63;
        bf16x8 v8 = *(const bf16x8*)(T + c * 132 + ch * 8);
        *(bf16x8*)(vTo + ((size_t)((bb * 16 + hh) * 64 + dd)) * 2048 + l0b + ch * 8) = v8;
      }
      return;
    }
  }

#pragma unroll
  for (int i = 0; i < 4; ++i) {
    int rowb = m0 + wr * 64 + 16 * i + quad * 4;
#pragma unroll
    for (int j = 0; j < 4; ++j) {
      int col = n0 + wc * 64 + 16 * j + l16;
      float bv = (zz == 0) ? bias[col] : 0.f;
#pragma unroll
      for (int r = 0; r < 4; ++r) {
        float v = acc[i][j][r] + bv;
        size_t idx = (size_t)(rowb + r) * N + col;
        if (zz != 0) {
          C2[idx] = v;  // raw f32 partial; consumer sums
        } else if (mode == 0) {
          ((bf16_t*)C)[idx] = (bf16_t)v;
        } else if (mode == 1) {
          ((bf16_t*)C)[idx] = (bf16_t)gelu_t(v);
        } else {
          ((float*)C)[idx] = v;
        }
      }
    }
  }
}

// ---------------- chunk-pipelined GEMM (FF1) ----------------
// C = gelu(A @ Bt^T + bias), bf16 out. 256x256 tile, 8 waves x (128x64),
// 2-slot dbuf (128KB, 1 block/CU). K-tile=64 staged as 4x16KB chunks
// interleaved with MFMA j-groups; two vmcnt(4)+barrier per K-tile.
__global__ __launch_bounds__(512, 2)
void gemm_8x(const bf16_t* __restrict__ A,
             const bf16_t* __restrict__ Bt,
             const float* __restrict__ bias,
             bf16_t* __restrict__ C,
             int M, int N, int K) {
  __shared__ bf16_t smem[65536];  // 128KB: slot s at s*32768:
                                  //   A-klo +0, A-khi +8192, B-klo +16384, B-khi +24576
  const int nbx = gridDim.x;
  int p = blockIdx.y * nbx + blockIdx.x;
  const int GM = 8;
  int group = p / (GM * nbx);
  int idx = p - group * (GM * nbx);
  const int by = group * GM + (idx & (GM - 1));
  const int bx = idx >> 3;
  const int n0 = bx * 256, m0 = by * 256;

  const int t = threadIdx.x;
  const int lane = t & 63, w = t >> 6;
  const int wr = w >> 2, wc = w & 3;     // 2 x 4 wave grid; wave C = 128x64
  const int quad = lane >> 4, l16 = lane & 15;

  f32x4 acc[8][4];
#pragma unroll
  for (int i = 0; i < 8; ++i)
#pragma unroll
    for (int j = 0; j < 4; ++j) acc[i][j] = (f32x4){0.f, 0.f, 0.f, 0.f};

  // DMA source offsets (chunk-XOR pre-swizzle); chunk regions are [*][32]
  const int r0 = t >> 2;
  const unsigned ksw = (((unsigned)t & 3u) ^ ((unsigned)(r0 >> 1) & 3u)) * 8u;
  const unsigned offR = (unsigned)r0 * (unsigned)K + ksw;

  const bf16_t* aB = A + (size_t)m0 * K;
  const bf16_t* bB = Bt + (size_t)n0 * K;

  // frag read offsets within a chunk region ([256 rows][32] swizzled)
  unsigned aoff[8], boff[4];
#pragma unroll
  for (int i = 0; i < 8; ++i) {
    int row = wr * 128 + 16 * i + l16;
    aoff[i] = (unsigned)(row * 32 + (quad ^ ((row >> 1) & 3)) * 8);
  }
#pragma unroll
  for (int j = 0; j < 4; ++j) {
    int row = wc * 64 + 16 * j + l16;
    boff[j] = (unsigned)(16384 + row * 32 + (quad ^ ((row >> 1) & 3)) * 8);
  }

  // stage one 16KB chunk (256 rows x 32 k) = 2 gld_lds passes of 128 rows
  auto stageChunk = [&](const bf16_t* src, int kk, int regionElem) {
    bf16_t* d = smem + regionElem;
    gld_lds16(src + kk + offR, d + t * 8);
    gld_lds16(src + kk + offR + (size_t)128 * K, d + t * 8 + 4096);
  };

  const int NT = K >> 6;   // K/64 tiles; NT >= 2

  // prologue: stage tile 0's 4 chunks; wait for klo pair (khi stays in flight)
  stageChunk(aB, 0, 0);
  stageChunk(bB, 0, 16384);
  stageChunk(aB, 32, 8192);
  stageChunk(bB, 32, 24576);
  vmwait(4);
  block_bar();

  for (int kt = 0; kt < NT; ++kt) {
    const int sb = (kt & 1) * 32768;         // compute slot base
    const int ss = ((kt + 1) & 1) * 32768;   // stage slot base
    const int ktk = (kt + 1) * 64;
    const bool st = (kt + 1 < NT);
    bf16x8 af[8], b0, b1;
    // ==== half 0 (k 0..31 of tile) ====
#pragma unroll
    for (int i = 0; i < 8; ++i) af[i] = *(const bf16x8*)(smem + sb + aoff[i]);
    b0 = *(const bf16x8*)(smem + sb + boff[0]);
    b1 = *(const bf16x8*)(smem + sb + boff[1]);
    if (st) stageChunk(aB, ktk, ss);                      // A-klo of kt+1
    __builtin_amdgcn_s_setprio(1);
#pragma unroll
    for (int i = 0; i < 8; ++i) {
      acc[i][0] = __builtin_amdgcn_mfma_f32_16x16x32_bf16(af[i], b0, acc[i][0], 0, 0, 0);
      acc[i][1] = __builtin_amdgcn_mfma_f32_16x16x32_bf16(af[i], b1, acc[i][1], 0, 0, 0);
    }
    __builtin_amdgcn_s_setprio(0);
    b0 = *(const bf16x8*)(smem + sb + boff[2]);
    b1 = *(const bf16x8*)(smem + sb + boff[3]);
    if (st) stageChunk(bB, ktk, ss + 16384);              // B-klo of kt+1
    __builtin_amdgcn_s_setprio(1);
#pragma unroll
    for (int i = 0; i < 8; ++i) {
      acc[i][2] = __builtin_amdgcn_mfma_f32_16x16x32_bf16(af[i], b0, acc[i][2], 0, 0, 0);
      acc[i][3] = __builtin_amdgcn_mfma_f32_16x16x32_bf16(af[i], b1, acc[i][3], 0, 0, 0);
    }
    __builtin_amdgcn_s_setprio(0);
    // outstanding: Akhi_kt,Bkhi_kt,Aklo',Bklo' (8) -> retire khi pair
    if (st) vmwait(4); else vmwait(0);
    block_bar();
    // ==== half 1 (k 32..63 of tile) ====
#pragma unroll
    for (int i = 0; i < 8; ++i) af[i] = *(const bf16x8*)(smem + sb + 8192 + aoff[i]);
    b0 = *(const bf16x8*)(smem + sb + 8192 + boff[0]);
    b1 = *(const bf16x8*)(smem + sb + 8192 + boff[1]);
    if (st) stageChunk(aB, ktk + 32, ss + 8192);          // A-khi of kt+1
    __builtin_amdgcn_s_setprio(1);
#pragma unroll
    for (int i = 0; i < 8; ++i) {
      acc[i][0] = __builtin_amdgcn_mfma_f32_16x16x32_bf16(af[i], b0, acc[i][0], 0, 0, 0);
      acc[i][1] = __builtin_amdgcn_mfma_f32_16x16x32_bf16(af[i], b1, acc[i][1], 0, 0, 0);
    }
    __builtin_amdgcn_s_setprio(0);
    b0 = *(const bf16x8*)(smem + sb + 8192 + boff[2]);
    b1 = *(const bf16x8*)(smem + sb + 8192 + boff[3]);
    if (st) stageChunk(bB, ktk + 32, ss + 24576);         // B-khi of kt+1
    __builtin_amdgcn_s_setprio(1);
#pragma unroll
    for (int i = 0; i < 8; ++i) {
      acc[i][2] = __builtin_amdgcn_mfma_f32_16x16x32_bf16(af[i], b0, acc[i][2], 0, 0, 0);
      acc[i][3] = __builtin_amdgcn_mfma_f32_16x16x32_bf16(af[i], b1, acc[i][3], 0, 0, 0);
    }
    __builtin_amdgcn_s_setprio(0);
    if (st) {
      // outstanding: Aklo',Bklo',Akhi',Bkhi' (8) -> retire klo pair
      vmwait(4);
      block_bar();
    }
  }

#pragma unroll
  for (int i = 0; i < 8; ++i) {
    int rowb = m0 + wr * 128 + 16 * i + quad * 4;
#pragma unroll
    for (int j = 0; j < 4; ++j) {
      int col = n0 + wc * 64 + 16 * j + l16;
      float bv = bias[col];
#pragma unroll
      for (int r = 0; r < 4; ++r) {
        float v = acc[i][j][r] + bv;
        C[(size_t)(rowb + r) * N + col] = (bf16_t)gelu_t(v);
      }
    }
  }
}

// ---------------- flash attention: 256q/block, 64q/wave, operand-swapped ----------------
// S^T[k][q] = K·(sc·Q)^T ; O^T[d][q] = V^T · P^T. KVBLK=64 double-buffered,
// counted vmwait(4); 64 KB LDS, 2 blocks/CU; each K/V A-frag read feeds the
// two q-half MFMAs (LDS + HBM traffic per work halved vs 128q/block).
// Denominator via MFMA(ones).
__global__ __launch_bounds__(256, 2) void attn_kernel(const bf16_t* __restrict__ qkv,
                                                      const bf16_t* __restrict__ vT,
                                                      bf16_t* __restrict__ ob) {
  __shared__ bf16_t smem[32768];  // 64 KB: [Ks(8KB)|Vts(8KB)] x2 slots | Qs(32KB)
  bf16_t* Qs = smem + 16384;      // [256 q][64 d]  unpadded, chunk-XOR swizzle
  const int qt = blockIdx.x, h = blockIdx.y, b = blockIdx.z;
  const int t = threadIdx.x, lane = t & 63, w = t >> 6;
  const int l32 = lane & 31, hi = lane >> 5;
  const size_t RS = 3 * HID;
  const int bh = b * NHEAD + h;

  const bf16_t* qbase = qkv + ((size_t)(b * LSEQ + qt * 256)) * RS + h * HD;
  const bf16_t* kbase = qkv + ((size_t)b * LSEQ) * RS + HID + h * HD;
  const bf16_t* vtbase = vT + (size_t)bh * HD * LSEQ;

  // stage Q [256][64] via DMA, source-swizzled
#pragma unroll
  for (int s = 0; s < 8; ++s) {
    int l = t + s * 256;
    int r = l >> 3, c8 = l & 7;
    gld_lds16(qbase + (size_t)r * RS + ((c8 ^ (r & 7)) * 8), Qs + l * 8);
  }
  __syncthreads();

  // hoist Q B-frags: wave w owns q in [64w, 64w+64); two 32-q halves A/B
  const float sc = 0.18033688011112042f;  // (1/sqrt(64)) * log2(e)
  bf16x8 bqA[4], bqB[4];
  {
    int qA = 64 * w + l32, qB = qA + 32;
#pragma unroll
    for (int c = 0; c < 4; ++c) {
      int y = 2 * c + hi;
      bf16x8 qa = *(const bf16x8*)(Qs + qA * 64 + ((y ^ (qA & 7)) * 8));
      bf16x8 qb = *(const bf16x8*)(Qs + qB * 64 + ((y ^ (qB & 7)) * 8));
#pragma unroll
      for (int e = 0; e < 8; ++e) {
        qa[e] = (bf16_t)((float)qa[e] * sc);
        qb[e] = (bf16_t)((float)qb[e] * sc);
      }
      bqA[c] = qa;
      bqB[c] = qb;
    }
  }

  // ones A-frag: with A==1, mfma gives D[m][q] = sum_k P^T[k][q]
  bf16x8 ones8;
#pragma unroll
  for (int e = 0; e < 8; ++e) ones8[e] = (bf16_t)1.0f;

  // stage K/V tile kt (64 rows) into slot: Ks [64 k][64 d], Vts [64 d][64 l]
  auto stageKV = [&](int slot, int kt) {
    bf16_t* Ks = smem + slot * 8192;
    bf16_t* Vts = Ks + 4096;
#pragma unroll
    for (int s = 0; s < 2; ++s) {
      int l = t + s * 256;
      int r = l >> 3, c8 = l & 7;
      gld_lds16(kbase + (size_t)(kt * 64 + r) * RS + ((c8 ^ (r & 7)) * 8), Ks + l * 8);
      gld_lds16(vtbase + (size_t)r * LSEQ + kt * 64 + ((c8 ^ (r & 7)) * 8), Vts + l * 8);
    }
  };

  f32x16 accOA[2], accOB[2], accSA, accSB, z16;
#pragma unroll
  for (int e = 0; e < 16; ++e) {
    accOA[0][e] = 0.f; accOA[1][e] = 0.f;
    accOB[0][e] = 0.f; accOB[1][e] = 0.f;
    accSA[e] = 0.f; accSB[e] = 0.f; z16[e] = 0.f;
  }

  constexpr int NT = LSEQ / 64;  // 32
  stageKV(0, 0);                 // 4 loads in flight

  for (int kt = 0; kt < NT; ++kt) {
    const int cs = kt & 1;
    if (kt + 1 < NT) {
      stageKV(1 - cs, kt + 1);   // issue next tile first (hides K/V latency)
      vmwait(4);                 // tile kt's 4 loads landed; kt+1's in flight
    } else {
      vmwait(0);
    }
    block_bar();                 // all waves' tile-kt loads visible
    const bf16_t* Ks = smem + cs * 8192;
    const bf16_t* Vts = Ks + 4096;

    // S^T rows 0..63 (this tile's k) x this wave's 64 q (two halves)
    f32x16 sA0, sA1, sB0, sB1;
    __builtin_amdgcn_s_setprio(1);
    {  // c = 0 peel: consume hoisted zero vec (no per-tile re-zeroing)
      int y = hi;
      int r0 = l32, r1 = 32 + l32;
      bf16x8 a0 = *(const bf16x8*)(Ks + r0 * 64 + ((y ^ (r0 & 7)) * 8));
      bf16x8 a1 = *(const bf16x8*)(Ks + r1 * 64 + ((y ^ (r1 & 7)) * 8));
      sA0 = __builtin_amdgcn_mfma_f32_32x32x16_bf16(a0, bqA[0], z16, 0, 0, 0);
      sA1 = __builtin_amdgcn_mfma_f32_32x32x16_bf16(a1, bqA[0], z16, 0, 0, 0);
      sB0 = __builtin_amdgcn_mfma_f32_32x32x16_bf16(a0, bqB[0], z16, 0, 0, 0);
      sB1 = __builtin_amdgcn_mfma_f32_32x32x16_bf16(a1, bqB[0], z16, 0, 0, 0);
    }
#pragma unroll
    for (int c = 1; c < 4; ++c) {
      int y = 2 * c + hi;
      int r0 = l32, r1 = 32 + l32;
      bf16x8 a0 = *(const bf16x8*)(Ks + r0 * 64 + ((y ^ (r0 & 7)) * 8));
      bf16x8 a1 = *(const bf16x8*)(Ks + r1 * 64 + ((y ^ (r1 & 7)) * 8));
      sA0 = __builtin_amdgcn_mfma_f32_32x32x16_bf16(a0, bqA[c], sA0, 0, 0, 0);
      sA1 = __builtin_amdgcn_mfma_f32_32x32x16_bf16(a1, bqA[c], sA1, 0, 0, 0);
      sB0 = __builtin_amdgcn_mfma_f32_32x32x16_bf16(a0, bqB[c], sB0, 0, 0, 0);
      sB1 = __builtin_amdgcn_mfma_f32_32x32x16_bf16(a1, bqB[c], sB1, 0, 0, 0);
    }
    __builtin_amdgcn_s_setprio(0);

    // p = exp2(s); pack to bf16 pairs; assemble P^T B-frags via permlane swaps
    unsigned pfA[2][2][4], pfB[2][2][4];  // [stile][c2][reg]
    auto mkpf = [&](f32x16& s0, f32x16& s1, unsigned (&pf)[2][2][4]) {
#pragma unroll
      for (int stile = 0; stile < 2; ++stile) {
        f32x16& sv = stile ? s1 : s0;
        float p[16];
#pragma unroll
        for (int e = 0; e < 16; ++e) p[e] = EXP2F(sv[e]);
        unsigned lo[4], hi_[4];
#pragma unroll
        for (int g = 0; g < 4; ++g) {
          lo[g] = pk_bf16(p[4 * g + 0], p[4 * g + 1]);
          hi_[g] = pk_bf16(p[4 * g + 2], p[4 * g + 3]);
        }
#pragma unroll
        for (int c2 = 0; c2 < 2; ++c2) {
          unsigned aL = lo[2 * c2], bL = lo[2 * c2 + 1];
          swap32(aL, bL);
          pf[stile][c2][0] = aL; pf[stile][c2][2] = bL;
          unsigned aH = hi_[2 * c2], bH = hi_[2 * c2 + 1];
          swap32(aH, bH);
          pf[stile][c2][1] = aH; pf[stile][c2][3] = bH;
        }
      }
    };
    mkpf(sA0, sA1, pfA);
    mkpf(sB0, sB1, pfB);

    // O^T += V^T · P^T (V-frag read shared by both q-halves); accS += ones·P^T
    __builtin_amdgcn_s_setprio(1);
#pragma unroll
    for (int dt = 0; dt < 2; ++dt)
#pragma unroll
      for (int stile = 0; stile < 2; ++stile)
#pragma unroll
        for (int c2 = 0; c2 < 2; ++c2) {
          int c8v = stile * 4 + c2 * 2 + hi;
          int rv = dt * 32 + l32;
          bf16x8 av = *(const bf16x8*)(Vts + rv * 64 + ((c8v ^ (rv & 7)) * 8));
          union { unsigned u[4]; bf16x8 v; } ba, bb;
          ba.u[0] = pfA[stile][c2][0]; ba.u[1] = pfA[stile][c2][1];
          ba.u[2] = pfA[stile][c2][2]; ba.u[3] = pfA[stile][c2][3];
          bb.u[0] = pfB[stile][c2][0]; bb.u[1] = pfB[stile][c2][1];
          bb.u[2] = pfB[stile][c2][2]; bb.u[3] = pfB[stile][c2][3];
          accOA[dt] = __builtin_amdgcn_mfma_f32_32x32x16_bf16(av, ba.v, accOA[dt], 0, 0, 0);
          accOB[dt] = __builtin_amdgcn_mfma_f32_32x32x16_bf16(av, bb.v, accOB[dt], 0, 0, 0);
        }
#pragma unroll
    for (int stile = 0; stile < 2; ++stile)
#pragma unroll
      for (int c2 = 0; c2 < 2; ++c2) {
        union { unsigned u[4]; bf16x8 v; } ba, bb;
        ba.u[0] = pfA[stile][c2][0]; ba.u[1] = pfA[stile][c2][1];
        ba.u[2] = pfA[stile][c2][2]; ba.u[3] = pfA[stile][c2][3];
        bb.u[0] = pfB[stile][c2][0]; bb.u[1] = pfB[stile][c2][1];
        bb.u[2] = pfB[stile][c2][2]; bb.u[3] = pfB[stile][c2][3];
        accSA = __builtin_amdgcn_mfma_f32_32x32x16_bf16(ones8, ba.v, accSA, 0, 0, 0);
        accSB = __builtin_amdgcn_mfma_f32_32x32x16_bf16(ones8, bb.v, accSB, 0, 0, 0);
      }
    __builtin_amdgcn_s_setprio(0);
    block_bar();  // reads of slot cs done -> next iter may stage into it
  }

  // denominators: every accS element = full sum over k for col q = l32
  float invA = 1.f / accSA[0];
  float invB = 1.f / accSB[0];

  // epilogue: O^T -> LDS (stride 68) -> coalesced global
  bf16_t* Osh = smem;  // [256 q][68]
  {
    int qA = 64 * w + l32, qB = qA + 32;
#pragma unroll
    for (int dt = 0; dt < 2; ++dt)
#pragma unroll
      for (int e = 0; e < 16; ++e) {
        int d = dt * 32 + (e & 3) + 8 * (e >> 2) + 4 * hi;
        Osh[qA * 68 + d] = (bf16_t)(accOA[dt][e] * invA);
        Osh[qB * 68 + d] = (bf16_t)(accOB[dt][e] * invB);
      }
  }
  __syncthreads();
#pragma unroll
  for (int s = 0; s < 8; ++s) {
    int l = t + s * 256;
    int r = l >> 3, c8 = l & 7;
    bf16x8 v = *(const bf16x8*)(Osh + r * 68 + c8 * 8);
    *(bf16x8*)(ob + ((size_t)(b * LSEQ + qt * 256 + r)) * HID + h * HD + c8 * 8) = v;
  }
}

// ---------------- residual add (2 or 3 way) + LayerNorm ----------------
__global__ __launch_bounds__(256) void resid_ln(const float* __restrict__ X,
                                                const float* __restrict__ Y,
                                                const float* __restrict__ Y2,
                                                const float* __restrict__ g,
                                                const float* __restrict__ be,
                                                float* __restrict__ outf,
                                                bf16_t* __restrict__ outb) {
  const int row = blockIdx.x;
  const int t = threadIdx.x;
  float4 a = ((const float4*)X)[(size_t)row * 256 + t];
  float4 bvec = ((const float4*)Y)[(size_t)row * 256 + t];
  float4 cvec = {0.f, 0.f, 0.f, 0.f};
  if (Y2) cvec = ((const float4*)Y2)[(size_t)row * 256 + t];
  float v0 = a.x + bvec.x + cvec.x, v1 = a.y + bvec.y + cvec.y;
  float v2 = a.z + bvec.z + cvec.z, v3 = a.w + bvec.w + cvec.w;
  float s = v0 + v1 + v2 + v3;
  float s2 = v0 * v0 + v1 * v1 + v2 * v2 + v3 * v3;
#pragma unroll
  for (int msk = 1; msk < 64; msk <<= 1) {
    s += __shfl_xor(s, msk, 64);
    s2 += __shfl_xor(s2, msk, 64);
  }
  __shared__ float red[8];
  int w = t >> 6;
  if ((t & 63) == 0) { red[w] = s; red[w + 4] = s2; }
  __syncthreads();
  s = red[0] + red[1] + red[2] + red[3];
  s2 = red[4] + red[5] + red[6] + red[7];
  float mu = s * (1.f / 1024.f);
  float var = s2 * (1.f / 1024.f) - mu * mu;
  float rstd = rsqrtf(var + 1e-5f);
  float4 gg = ((const float4*)g)[t];
  float4 bb = ((const float4*)be)[t];
  float o0 = (v0 - mu) * rstd * gg.x + bb.x;
  float o1 = (v1 - mu) * rstd * gg.y + bb.y;
  float o2 = (v2 - mu) * rstd * gg.z + bb.z;
  float o3 = (v3 - mu) * rstd * gg.w + bb.w;
  float4 o = {o0, o1, o2, o3};
  ((float4*)outf)[(size_t)row * 256 + t] = o;
  if (outb) {
    bf16x4 ob4;
    ob4[0] = (bf16_t)o0; ob4[1] = (bf16_t)o1; ob4[2] = (bf16_t)o2; ob4[3] = (bf16_t)o3;
    ((bf16x4*)outb)[(size_t)row * 256 + t] = ob4;
  }
}

// ---------------- host ----------------
extern "C" void kernel_launch(void* const* d_in, const int* in_sizes, int n_in,
                              void* d_out, int out_size, void* d_ws, size_t ws_size,
                              hipStream_t stream) {
  const float* x     = (const float*)d_in[0];
  const float* Wqkv  = (const float*)d_in[1];
  const float* bqkv  = (const float*)d_in[2];
  const float* Wproj = (const float*)d_in[3];
  const float* bproj = (const float*)d_in[4];
  const float* W1    = (const float*)d_in[5];
  const float* b1    = (const float*)d_in[6];
  const float* W2    = (const float*)d_in[7];
  const float* b2    = (const float*)d_in[8];
  const float* g1    = (const float*)d_in[9];
  const float* be1   = (const float*)d_in[10];
  const float* g2    = (const float*)d_in[11];
  const float* be2   = (const float*)d_in[12];
  float* out = (float*)d_out;

  // Workspace layout (184 MB, alias-planned):
  //   [0,8M)    w2T      (setup -> FF2)
  //   [8,40M)   h        (proj z1 partial -> LN1 reads+overwrites; -> LN2)
  //   [40,72M)  a_f2     (proj z0 -> LN1; FF2 z0 -> LN2)
  //   [72,136M) qkv_ff   (qkvb: QKV -> attn; ff1b: FF1 -> FF2)
  //   [136,184M) E:
  //     E+0:  wqkvT 6M; E+6M: wprojT 2M; E+8M: w1T 8M; E+16M: xb_ob 16M
  //       -> all dead by FF2: f2b (FF2 z1 partial, 32M) overlays E..E+32M
  //     E+32M: hb/vTg 16M (vTg: QKV -> attn; hb: LN1 -> FF1)
  char* ws = (char*)d_ws;
  bf16_t* w2T    = (bf16_t*)(ws);
  float*  h      = (float*) (ws + ((size_t)8 << 20));
  float*  a_f2   = (float*) (ws + ((size_t)40 << 20));
  bf16_t* qkv_ff = (bf16_t*)(ws + ((size_t)72 << 20));
  char*   E      = ws + ((size_t)136 << 20);
  bf16_t* wqkvT  = (bf16_t*)(E);
  bf16_t* wprojT = (bf16_t*)(E + ((size_t)6 << 20));
  bf16_t* w1T    = (bf16_t*)(E + ((size_t)8 << 20));
  char*   xb_ob  = E + ((size_t)16 << 20);
  bf16_t* hb     = (bf16_t*)(E + ((size_t)32 << 20));
  float*  f2b    = (float*)E;   // FF2 z1 partial: overlays wqkvT..xb_ob (dead)

  bf16_t* xb    = (bf16_t*)xb_ob;
  bf16_t* ob    = (bf16_t*)xb_ob;
  bf16_t* qkvb  = qkv_ff;
  bf16_t* ff1b  = qkv_ff;
  float*  attnf = a_f2;
  float*  ff2f  = a_f2;
  bf16_t* vTg   = hb;  // alias: vT live only qkv->attn; hb live only after LN1

  dim3 blk(256);
  dim3 blk512(512);
  transpose_cvt<<<dim3(3072 / 32, 1024 / 32), blk, 0, stream>>>(Wqkv, wqkvT, 1024, 3072);
  transpose_cvt<<<dim3(1024 / 32, 1024 / 32), blk, 0, stream>>>(Wproj, wprojT, 1024, 1024);
  transpose_cvt<<<dim3(4096 / 32, 1024 / 32), blk, 0, stream>>>(W1, w1T, 1024, 4096);
  transpose_cvt<<<dim3(1024 / 32, 4096 / 32), blk, 0, stream>>>(W2, w2T, 4096, 1024);
  cvt_bf16<<<MROWS * HID / 4 / 256, blk, 0, stream>>>(x, xb, MROWS * HID / 4);

  // QKV: V third transposed via LDS in-epilogue straight to vTg (coalesced)
  gemm_k<128, 256, 512><<<dim3(3072 / 256, MROWS / 128), blk512, 0, stream>>>(
      xb, wqkvT, bqkv, qkvb, nullptr, vTg, MROWS, 3072, 1024, 0);
  attn_kernel<<<dim3(LSEQ / 256, NHEAD, BATCH), blk, 0, stream>>>(qkvb, vTg, ob);
  // proj split-K x2: z0 -> attnf(+bias), z1 -> h (raw partial; LN1 sums)
  gemm_k<128, 256, 512><<<dim3(1024 / 256, MROWS / 128, 2), blk512, 0, stream>>>(
      ob, wprojT, bproj, attnf, h, nullptr, MROWS, 1024, 1024, 2);
  resid_ln<<<MROWS, blk, 0, stream>>>(x, attnf, h, g1, be1, h, hb);
  // FF1: chunk-pipelined 256x256 kernel (gelu fused)
  gemm_8x<<<dim3(4096 / 256, MROWS / 256), blk512, 0, stream>>>(
      hb, w1T, b1, ff1b, MROWS, 4096, 1024);
  // FF2 split-K x2: z0 -> ff2f (+bias), z1 -> f2b (raw partial)
  gemm_k<128, 256, 512><<<dim3(1024 / 256, MROWS / 128, 2), blk512, 0, stream>>>(
      ff1b, w2T, b2, ff2f, f2b, nullptr, MROWS, 1024, 4096, 2);
  resid_ln<<<MROWS, blk, 0, stream>>>(h, ff2f, f2b, g2, be2, out, (bf16_t*)nullptr);
}